// Round 1
// baseline (13758.856 us; speedup 1.0000x reference)
//
#include <hip/hip_runtime.h>
#include <math.h>

#define DIM     1024
#define S_LEN   2048
#define BATCH   2
#define NTOK    4096      // BATCH*S_LEN
#define NHEADS  16
#define NKVH    4
#define HD      64
#define NEXP    8
#define HIDDEN  2816
#define VOCABSZ 32000
#define RMSEPS  1e-6f

// padded MoE segment capacity: 8192 rows + 8*127 pad, rounded to 128 -> 9216
#define MOE_ROWS 9216

// ---------------------------------------------------------------------------
// embedding gather
__global__ void embed_k(const int* __restrict__ tokens, const float* __restrict__ emb,
                        float* __restrict__ h) {
    int t = blockIdx.x;
    int tok = tokens[t];
    const float* er = emb + (long)tok * DIM;
    float* hr = h + (long)t * DIM;
    for (int d = threadIdx.x; d < DIM; d += 256) hr[d] = er[d];
}

// ---------------------------------------------------------------------------
// rmsnorm: one block per token
__global__ void rmsnorm_k(const float* __restrict__ x, const float* __restrict__ w,
                          float* __restrict__ o) {
    int t = blockIdx.x;
    const float* xr = x + (long)t * DIM;
    float ss = 0.f;
    for (int d = threadIdx.x; d < DIM; d += 256) { float v = xr[d]; ss += v * v; }
    __shared__ float red[256];
    red[threadIdx.x] = ss;
    __syncthreads();
    for (int s = 128; s > 0; s >>= 1) {
        if (threadIdx.x < s) red[threadIdx.x] += red[threadIdx.x + s];
        __syncthreads();
    }
    float scale = rsqrtf(red[0] / (float)DIM + RMSEPS);
    float* orow = o + (long)t * DIM;
    for (int d = threadIdx.x; d < DIM; d += 256) orow[d] = xr[d] * scale * w[d];
}

// ---------------------------------------------------------------------------
// RoPE in-place. x layout [t][nheads][64]; pair index i in 0..31
__global__ void rope_k(float* __restrict__ x, int hshift, const int* __restrict__ sposp,
                       int total) {
    int idx = blockIdx.x * 256 + threadIdx.x;
    if (idx >= total) return;
    int i  = idx & 31;
    int th = idx >> 5;                   // t*nheads + h
    int t  = th >> hshift;
    int s  = t & (S_LEN - 1);
    int pos = s + sposp[0];
    // inv = 1 / theta^(2i/64);  log2(10000) = 13.28771238f
    float inv = exp2f(-((float)i / 32.f) * 13.28771238f);
    float ang = (float)pos * inv;
    float c = cosf(ang), sn = sinf(ang);
    float* p = x + ((long)th << 6) + 2 * i;
    float x1 = p[0], x2 = p[1];
    p[0] = x1 * c - x2 * sn;
    p[1] = x1 * sn + x2 * c;
}

// ---------------------------------------------------------------------------
// flash attention, one wave per query row. grid = (BATCH*NHEADS, S_LEN/4), block 256
__global__ __launch_bounds__(256) void attn_k(const float* __restrict__ q,
                                              const float* __restrict__ k,
                                              const float* __restrict__ v,
                                              float* __restrict__ o) {
    int bh = blockIdx.x;
    int b = bh >> 4, h = bh & 15;
    int hkv = h >> 2;
    int w = threadIdx.x >> 6;
    int lane = threadIdx.x & 63;
    int sq = blockIdx.y * 4 + w;

    __shared__ float qs[4][64];
    qs[w][lane] = q[((long)(b * S_LEN + sq) * NHEADS + h) * HD + lane];
    __syncthreads();   // single barrier; all waves reach exactly once

    float m = -1e30f, l = 0.f, acc = 0.f;   // acc holds o[lane]
    int ntile = (sq >> 6) + 1;
    const float scale = 0.125f;             // 1/sqrt(64)

    for (int kt = 0; kt < ntile; ++kt) {
        int kpos = kt * 64 + lane;
        const float* krow = k + ((long)(b * S_LEN + kpos) * NKVH + hkv) * HD;
        float s = 0.f;
#pragma unroll
        for (int d4 = 0; d4 < 16; ++d4) {
            float4 kv4 = *(const float4*)(krow + d4 * 4);
            float4 q4  = *(const float4*)&qs[w][d4 * 4];
            s += kv4.x * q4.x + kv4.y * q4.y + kv4.z * q4.z + kv4.w * q4.w;
        }
        s *= scale;
        if (kpos > sq) s = -1e30f;
        float mt = s;
#pragma unroll
        for (int off = 32; off > 0; off >>= 1) mt = fmaxf(mt, __shfl_xor(mt, off));
        float mnew = fmaxf(m, mt);
        float p = expf(s - mnew);
        float corr = expf(m - mnew);
        float psum = p;
#pragma unroll
        for (int off = 32; off > 0; off >>= 1) psum += __shfl_xor(psum, off);
        l = l * corr + psum;
        m = mnew;
        acc *= corr;
        const float* vbase = v + ((long)(b * S_LEN + kt * 64) * NKVH + hkv) * HD + lane;
#pragma unroll 8
        for (int j = 0; j < 64; ++j) {
            float pj = __shfl(p, j);
            acc += pj * vbase[(long)j * (NKVH * HD)];
        }
    }
    o[((long)(b * S_LEN + sq) * NHEADS + h) * HD + lane] = acc / l;
}

// ---------------------------------------------------------------------------
// gate: logits = xn @ gate_w (1024x8), softmax, top-2, renormalize
__global__ void gate_k(const float* __restrict__ xn, const float* __restrict__ gw,
                       int* __restrict__ tke, float* __restrict__ tkw,
                       int* __restrict__ cnt) {
    int t = blockIdx.x;
    __shared__ float pl[256];
    __shared__ float lg[8];
    int e = threadIdx.x & 7, c = threadIdx.x >> 3;
    const float* xr = xn + (long)t * DIM;
    float s = 0.f;
    for (int i = 0; i < DIM / 32; ++i) {
        int d = c + i * 32;
        s += xr[d] * gw[d * 8 + e];
    }
    pl[threadIdx.x] = s;
    __syncthreads();
    if (threadIdx.x < 8) {
        float sum = 0.f;
        for (int c2 = 0; c2 < 32; ++c2) sum += pl[c2 * 8 + threadIdx.x];
        lg[threadIdx.x] = sum;
    }
    __syncthreads();
    if (threadIdx.x == 0) {
        float mx = lg[0];
        for (int i = 1; i < 8; ++i) mx = fmaxf(mx, lg[i]);
        float pe[8];
        for (int i = 0; i < 8; ++i) pe[i] = expf(lg[i] - mx);
        int i0 = 0;
        for (int i = 1; i < 8; ++i) if (pe[i] > pe[i0]) i0 = i;
        int i1 = -1;
        for (int i = 0; i < 8; ++i) {
            if (i == i0) continue;
            if (i1 < 0 || pe[i] > pe[i1]) i1 = i;
        }
        float w0 = pe[i0], w1 = pe[i1];
        float wsum = w0 + w1;
        w0 /= wsum; w1 /= wsum;
        tke[2 * t] = i0; tke[2 * t + 1] = i1;
        tkw[2 * t] = w0; tkw[2 * t + 1] = w1;
        atomicAdd(&cnt[i0], 1);
        atomicAdd(&cnt[i1], 1);
    }
}

// padded prefix sums of expert counts (pad each segment to 128 rows)
__global__ void offs_k(const int* __restrict__ cnt, int* __restrict__ offs) {
    if (threadIdx.x == 0) {
        int o = 0;
        for (int e = 0; e < NEXP; ++e) { offs[e] = o; o += (cnt[e] + 127) & ~127; }
        offs[NEXP] = o;
    }
}

// per-token slot assignment
__global__ void fill_k(const int* __restrict__ tke, const float* __restrict__ tkw,
                       const int* __restrict__ offs, int* __restrict__ fillc,
                       int* __restrict__ rowidx, int* __restrict__ tslot) {
    int t = blockIdx.x * 256 + threadIdx.x;
    if (t >= NTOK) return;
    for (int kk = 0; kk < 2; ++kk) {
        int e = tke[2 * t + kk];
        int pos = atomicAdd(&fillc[e], 1);
        int slot = offs[e] + pos;
        rowidx[slot] = t;
        tslot[2 * t + kk] = slot;
    }
}

// h[t] += w0*eout[s0] + w1*eout[s1]
__global__ void combine_k(const int* __restrict__ tslot, const float* __restrict__ tkw,
                          const float* __restrict__ eout, float* __restrict__ h) {
    int t = blockIdx.x;
    int s0 = tslot[2 * t], s1 = tslot[2 * t + 1];
    float w0 = tkw[2 * t], w1 = tkw[2 * t + 1];
    float* hr = h + (long)t * DIM;
    const float* e0 = eout + (long)s0 * DIM;
    const float* e1 = eout + (long)s1 * DIM;
    for (int d = threadIdx.x; d < DIM; d += 256)
        hr[d] += w0 * e0[d] + w1 * e1[d];
}

// in-place silu-mul over the up-projection scratch: x1 = silu(x1) * x3
// hh2 row layout: [ x1 (2816) | x3 (2816) ], one block per row
__global__ void silumul_k(float* __restrict__ hh2) {
    int r = blockIdx.x;
    float* x1 = hh2 + (long)r * (2 * HIDDEN);
    const float* x3 = x1 + HIDDEN;
    for (int c = threadIdx.x; c < HIDDEN; c += 256) {
        float a = x1[c];
        x1[c] = a / (1.f + expf(-a)) * x3[c];
    }
}

// ---------------------------------------------------------------------------
// tiled fp32 GEMM: 128x128 tile, BK=16, 256 threads, 8x8 per thread.
// LDS-intensity: 64 FMA per 4 ds_read_b128 (2 FLOP/B) vs 16/3 in the old 64x64
// kernel — the old one was LDS-read-bound at ~40% of fp32 FMA peak.
// Column split: logical col n < Nsplit -> B/C at col n, else B2/C2 at n-Nsplit.
//   (Nsplit must be a multiple of 128, or == N to disable. Both halves share
//    ldb/ldc.)  Used to fuse K|V projections and w1|w3 up-projections.
// MODE 0: C = A@B
// MODE 1: C += A@B
// MODE 2: expert-segmented m-tiles, A rows gathered via rowidx
// MODE 3: expert-segmented m-tiles, A rows contiguous
template <int MODE>
__global__ __launch_bounds__(256, 3) void gemm_k(
    const float* __restrict__ A, const float* __restrict__ B,
    const float* __restrict__ B2, float* __restrict__ C, float* __restrict__ C2,
    int N, int Nsplit, int K, int lda, int ldb, int ldc,
    const int* __restrict__ offs, const int* __restrict__ cnt,
    const int* __restrict__ rowidx) {
    __shared__ __align__(16) float As[16][132];   // k-major, +4 pad breaks write conflicts
    __shared__ __align__(16) float Bs[16][132];

    int n0 = blockIdx.x * 128, m0 = blockIdx.y * 128;
    const float* Bbase = B;
    float* Cbase = C;
    int ncol = n0;
    if (n0 >= Nsplit) { Bbase = B2; Cbase = C2; ncol = n0 - Nsplit; }

    int vr = 128;
    if (MODE >= 2) {
        int e = -1;
#pragma unroll
        for (int i = 0; i < NEXP; ++i)
            if (m0 >= offs[i] && m0 < offs[i + 1]) e = i;
        if (e < 0) return;
        vr = offs[e] + cnt[e] - m0;
        if (vr <= 0) return;
        if (vr > 128) vr = 128;
        Bbase += (long)e * K * ldb;
    }
    const float* Bp = Bbase + ncol;
    float* Cp = Cbase + ncol;

    int tid = threadIdx.x;
    int tx = tid & 15, ty = tid >> 4;

    // A staging: each thread loads rows r0 and r0+64, k-quad kq..kq+3
    int r0 = tid >> 2, kq = (tid & 3) * 4;
    long aoff0, aoff1;
    if (MODE == 2) {
        int g0 = (r0 < vr) ? rowidx[m0 + r0] : 0;
        int g1 = (r0 + 64 < vr) ? rowidx[m0 + r0 + 64] : 0;
        aoff0 = (long)g0 * lda;
        aoff1 = (long)g1 * lda;
    } else {
        aoff0 = (long)(m0 + r0) * lda;
        aoff1 = (long)(m0 + r0 + 64) * lda;
    }
    // B staging: each thread loads row bk, col quads bn4 and bn4+64
    int bk = tid >> 4, bn4 = (tid & 15) * 4;

    float acc[8][8] = {{0.f}};

    for (int k0 = 0; k0 < K; k0 += 16) {
        float4 av0 = *(const float4*)(A + aoff0 + k0 + kq);
        float4 av1 = *(const float4*)(A + aoff1 + k0 + kq);
        const float* brow = Bp + (long)(k0 + bk) * ldb + bn4;
        float4 bv0 = *(const float4*)(brow);
        float4 bv1 = *(const float4*)(brow + 64);
        __syncthreads();
        As[kq + 0][r0] = av0.x;
        As[kq + 1][r0] = av0.y;
        As[kq + 2][r0] = av0.z;
        As[kq + 3][r0] = av0.w;
        As[kq + 0][r0 + 64] = av1.x;
        As[kq + 1][r0 + 64] = av1.y;
        As[kq + 2][r0 + 64] = av1.z;
        As[kq + 3][r0 + 64] = av1.w;
        *(float4*)&Bs[bk][bn4] = bv0;
        *(float4*)&Bs[bk][bn4 + 64] = bv1;
        __syncthreads();
#pragma unroll
        for (int kk = 0; kk < 16; ++kk) {
            float4 a0 = *(const float4*)&As[kk][ty * 4];
            float4 a1 = *(const float4*)&As[kk][ty * 4 + 64];
            float4 b0 = *(const float4*)&Bs[kk][tx * 4];
            float4 b1 = *(const float4*)&Bs[kk][tx * 4 + 64];
            float aa[8] = {a0.x, a0.y, a0.z, a0.w, a1.x, a1.y, a1.z, a1.w};
            float bb[8] = {b0.x, b0.y, b0.z, b0.w, b1.x, b1.y, b1.z, b1.w};
#pragma unroll
            for (int i = 0; i < 8; ++i)
#pragma unroll
                for (int j = 0; j < 8; ++j) acc[i][j] += aa[i] * bb[j];
        }
    }

#pragma unroll
    for (int i = 0; i < 8; ++i) {
        int r = (i < 4) ? (ty * 4 + i) : (ty * 4 + i - 4 + 64);
        if (MODE >= 2 && r >= vr) continue;
        float* cp = Cp + (long)(m0 + r) * ldc + tx * 4;
        float4 v0 = make_float4(acc[i][0], acc[i][1], acc[i][2], acc[i][3]);
        float4 v1 = make_float4(acc[i][4], acc[i][5], acc[i][6], acc[i][7]);
        if (MODE == 1) {
            float4 o0 = *(const float4*)cp;
            float4 o1 = *(const float4*)(cp + 64);
            v0.x += o0.x; v0.y += o0.y; v0.z += o0.z; v0.w += o0.w;
            v1.x += o1.x; v1.y += o1.y; v1.z += o1.z; v1.w += o1.w;
        }
        *(float4*)cp = v0;
        *(float4*)(cp + 64) = v1;
    }
}

// ---------------------------------------------------------------------------
extern "C" void kernel_launch(void* const* d_in, const int* in_sizes, int n_in,
                              void* d_out, int out_size, void* d_ws, size_t ws_size,
                              hipStream_t stream) {
    const int*   tokens = (const int*)d_in[0];
    const int*   sposp  = (const int*)d_in[1];
    const float* emb    = (const float*)d_in[2];
    const float* anw    = (const float*)d_in[3];
    const float* wq     = (const float*)d_in[4];
    const float* wk     = (const float*)d_in[5];
    const float* wv     = (const float*)d_in[6];
    const float* wo     = (const float*)d_in[7];
    const float* fnw    = (const float*)d_in[8];
    const float* gw     = (const float*)d_in[9];
    const float* w1     = (const float*)d_in[10];
    const float* w2     = (const float*)d_in[11];
    const float* w3     = (const float*)d_in[12];
    const float* nw     = (const float*)d_in[13];
    const float* ow     = (const float*)d_in[14];
    float* out = (float*)d_out;

    char* wsb = (char*)d_ws;
    float* h  = (float*)wsb;                 wsb += (long)NTOK * DIM * 4;
    float* xn = (float*)wsb;                 wsb += (long)NTOK * DIM * 4;
    float* q  = (float*)wsb;                 wsb += (long)NTOK * DIM * 4;
    float* kb = (float*)wsb;                 wsb += (long)NTOK * NKVH * HD * 4;
    float* vb = (float*)wsb;                 wsb += (long)NTOK * NKVH * HD * 4;
    float* ao = (float*)wsb;                 wsb += (long)NTOK * DIM * 4;
    float* tkw = (float*)wsb;                wsb += (long)NTOK * 2 * 4;
    int* tke    = (int*)wsb;                 wsb += (long)NTOK * 2 * 4;
    int* tslot  = (int*)wsb;                 wsb += (long)NTOK * 2 * 4;
    int* rowidx = (int*)wsb;                 wsb += (long)MOE_ROWS * 4;
    int* cnt    = (int*)wsb;                 wsb += 8 * 4;
    int* fillc  = (int*)wsb;                 wsb += 8 * 4;
    int* offs   = (int*)wsb;                 wsb += 16 * 4;

    // big MoE scratch lives in d_out (fully overwritten by final logits GEMM)
    // hh2: MOE_ROWS x 5632  raw [x@w1 | x@w3], silu-mul'd in place (first half)
    // eout: MOE_ROWS x DIM  expert outputs
    float* hh2  = out;
    float* eout = out + (long)MOE_ROWS * (2 * HIDDEN);
    // usage: 9216*(5632+1024)*4B = 245 MB < out_size (4096*32000*4B = 524 MB)

    embed_k<<<NTOK, 256, 0, stream>>>(tokens, emb, h);

    for (int l = 0; l < 2; ++l) {
        const float* wq_l = wq + (long)l * DIM * DIM;
        const float* wk_l = wk + (long)l * DIM * (NKVH * HD);
        const float* wv_l = wv + (long)l * DIM * (NKVH * HD);
        const float* wo_l = wo + (long)l * DIM * DIM;
        const float* gw_l = gw + (long)l * DIM * NEXP;
        const float* w1_l = w1 + (long)l * NEXP * DIM * HIDDEN;
        const float* w2_l = w2 + (long)l * NEXP * HIDDEN * DIM;
        const float* w3_l = w3 + (long)l * NEXP * DIM * HIDDEN;

        // attention
        rmsnorm_k<<<NTOK, 256, 0, stream>>>(h, anw + l * DIM, xn);
        gemm_k<0><<<dim3(DIM / 128, NTOK / 128), 256, 0, stream>>>(
            xn, wq_l, nullptr, q, nullptr,
            DIM, DIM, DIM, DIM, DIM, DIM, nullptr, nullptr, nullptr);
        // fused K|V projection (column split at 256)
        gemm_k<0><<<dim3((2 * NKVH * HD) / 128, NTOK / 128), 256, 0, stream>>>(
            xn, wk_l, wv_l, kb, vb,
            2 * NKVH * HD, NKVH * HD, DIM, DIM, NKVH * HD, NKVH * HD,
            nullptr, nullptr, nullptr);
        rope_k<<<(NTOK * NHEADS * 32) / 256, 256, 0, stream>>>(q, 4, sposp, NTOK * NHEADS * 32);
        rope_k<<<(NTOK * NKVH * 32) / 256, 256, 0, stream>>>(kb, 2, sposp, NTOK * NKVH * 32);
        attn_k<<<dim3(BATCH * NHEADS, S_LEN / 4), 256, 0, stream>>>(q, kb, vb, ao);
        gemm_k<1><<<dim3(DIM / 128, NTOK / 128), 256, 0, stream>>>(
            ao, wo_l, nullptr, h, nullptr,
            DIM, DIM, DIM, DIM, DIM, DIM, nullptr, nullptr, nullptr);

        // MoE
        rmsnorm_k<<<NTOK, 256, 0, stream>>>(h, fnw + l * DIM, xn);
        hipMemsetAsync(cnt, 0, 16 * sizeof(int), stream);  // cnt + fillc
        gate_k<<<NTOK, 256, 0, stream>>>(xn, gw_l, tke, tkw, cnt);
        offs_k<<<1, 64, 0, stream>>>(cnt, offs);
        fill_k<<<NTOK / 256, 256, 0, stream>>>(tke, tkw, offs, fillc, rowidx, tslot);
        // up: hh2 = [xg @ w1 | xg @ w3], gathered rows, column split at 2816
        gemm_k<2><<<dim3((2 * HIDDEN) / 128, MOE_ROWS / 128), 256, 0, stream>>>(
            xn, w1_l, w3_l, hh2, hh2 + HIDDEN,
            2 * HIDDEN, HIDDEN, DIM, DIM, HIDDEN, 2 * HIDDEN, offs, cnt, rowidx);
        silumul_k<<<MOE_ROWS, 256, 0, stream>>>(hh2);
        // down: eout = hh2[:, :2816] @ w2   (lda = 5632)
        gemm_k<3><<<dim3(DIM / 128, MOE_ROWS / 128), 256, 0, stream>>>(
            hh2, w2_l, nullptr, eout, nullptr,
            DIM, DIM, HIDDEN, 2 * HIDDEN, DIM, DIM, offs, cnt, nullptr);
        combine_k<<<NTOK, 256, 0, stream>>>(tslot, tkw, eout, h);
    }

    // final norm + logits
    rmsnorm_k<<<NTOK, 256, 0, stream>>>(h, nw, xn);
    gemm_k<0><<<dim3(VOCABSZ / 128, NTOK / 128), 256, 0, stream>>>(
        xn, ow, nullptr, out, nullptr,
        VOCABSZ, VOCABSZ, DIM, DIM, VOCABSZ, VOCABSZ, nullptr, nullptr, nullptr);
}

// Round 2
// 9444.592 us; speedup vs baseline: 1.4568x; 1.4568x over previous
//
#include <hip/hip_runtime.h>
#include <math.h>

#define DIM     1024
#define S_LEN   2048
#define BATCH   2
#define NTOK    4096      // BATCH*S_LEN
#define NHEADS  16
#define NKVH    4
#define HD      64
#define NEXP    8
#define HIDDEN  2816
#define VOCABSZ 32000
#define RMSEPS  1e-6f

// padded MoE segment capacity: 8192 rows + 8*127 pad, rounded to 128 -> 9216
#define MOE_ROWS 9216

// ---------------------------------------------------------------------------
// embedding gather
__global__ void embed_k(const int* __restrict__ tokens, const float* __restrict__ emb,
                        float* __restrict__ h) {
    int t = blockIdx.x;
    int tok = tokens[t];
    const float* er = emb + (long)tok * DIM;
    float* hr = h + (long)t * DIM;
    for (int d = threadIdx.x; d < DIM; d += 256) hr[d] = er[d];
}

// ---------------------------------------------------------------------------
// rmsnorm: one block per token
__global__ void rmsnorm_k(const float* __restrict__ x, const float* __restrict__ w,
                          float* __restrict__ o) {
    int t = blockIdx.x;
    const float* xr = x + (long)t * DIM;
    float ss = 0.f;
    for (int d = threadIdx.x; d < DIM; d += 256) { float v = xr[d]; ss += v * v; }
    __shared__ float red[256];
    red[threadIdx.x] = ss;
    __syncthreads();
    for (int s = 128; s > 0; s >>= 1) {
        if (threadIdx.x < s) red[threadIdx.x] += red[threadIdx.x + s];
        __syncthreads();
    }
    float scale = rsqrtf(red[0] / (float)DIM + RMSEPS);
    float* orow = o + (long)t * DIM;
    for (int d = threadIdx.x; d < DIM; d += 256) orow[d] = xr[d] * scale * w[d];
}

// ---------------------------------------------------------------------------
// RoPE in-place. x layout [t][nheads][64]; pair index i in 0..31
__global__ void rope_k(float* __restrict__ x, int hshift, const int* __restrict__ sposp,
                       int total) {
    int idx = blockIdx.x * 256 + threadIdx.x;
    if (idx >= total) return;
    int i  = idx & 31;
    int th = idx >> 5;                   // t*nheads + h
    int t  = th >> hshift;
    int s  = t & (S_LEN - 1);
    int pos = s + sposp[0];
    // inv = 1 / theta^(2i/64);  log2(10000) = 13.28771238f
    float inv = exp2f(-((float)i / 32.f) * 13.28771238f);
    float ang = (float)pos * inv;
    float c = cosf(ang), sn = sinf(ang);
    float* p = x + ((long)th << 6) + 2 * i;
    float x1 = p[0], x2 = p[1];
    p[0] = x1 * c - x2 * sn;
    p[1] = x1 * sn + x2 * c;
}

// ---------------------------------------------------------------------------
// block-flash attention: one block = one (b,h) x 64 query rows, 256 threads.
// Thread grid: tx = tid>>4 (owns q cols tx*4..+3), ty = tid&15 (owns k/d rows ty*4..+3).
// Per 64-key tile:
//   GEMM1: T[kpos][q] = K_tile @ Q^T  (4x4 micro-tile per thread)
//   online softmax along kpos: column stats reduced via shfl_xor in 16-lane group
//   P^T written to LDS (overlays dead K buffer)
//   GEMM2: O^T[d][q] += V^T @ P^T
// LDS 52 KB -> 3 blocks/CU. Heavy blocks (large q0) scheduled first via y-reversal.
__global__ __launch_bounds__(256, 3) void attn_fa_k(const float* __restrict__ q,
                                                    const float* __restrict__ k,
                                                    const float* __restrict__ v,
                                                    float* __restrict__ o) {
    __shared__ __align__(16) float Qs[64][68];    // Q^T: Qs[d][q]
    __shared__ __align__(16) float KPs[64][68];   // K^T: [d][kpos], then P^T: [kpos][q]
    __shared__ __align__(16) float Vs[64][68];    // V:   [kpos][d]

    int bh = blockIdx.x;
    int b = bh >> 4, h = bh & 15;
    int hkv = h >> 2;
    int by = gridDim.y - 1 - blockIdx.y;          // heavy (causal-long) blocks first
    int q0 = by * 64;
    int tid = threadIdx.x;
    int tx = tid >> 4, ty = tid & 15;

    // stage Q^T (transposed write: 2-way bank conflicts = free)
    {
        int r = tid >> 2, kq = tid & 3;
        const float* qrow = q + (long)(b * S_LEN + q0 + r) * DIM + h * HD;
#pragma unroll
        for (int rd = 0; rd < 4; ++rd) {
            int dq = kq * 4 + rd * 16;
            float4 val = *(const float4*)(qrow + dq);
            Qs[dq + 0][r] = val.x;
            Qs[dq + 1][r] = val.y;
            Qs[dq + 2][r] = val.z;
            Qs[dq + 3][r] = val.w;
        }
    }

    float acc[4][4] = {{0.f}};                    // O^T[d=ty*4+i][q=tx*4+j]
    float mreg[4], lreg[4];
#pragma unroll
    for (int j = 0; j < 4; ++j) { mreg[j] = -1e30f; lreg[j] = 0.f; }
    const float scale = 0.125f;                   // 1/sqrt(64)

    for (int kt = 0; kt <= by; ++kt) {
        // ---- stage K^T and V tile (issue global loads before the barrier) ----
        int r = tid >> 2, kq = tid & 3;
        const float* krow = k + (long)(b * S_LEN + kt * 64 + r) * (NKVH * HD) + hkv * HD;
        const float* vrow = v + (long)(b * S_LEN + kt * 64 + r) * (NKVH * HD) + hkv * HD;
        float4 kv[4], vv[4];
#pragma unroll
        for (int rd = 0; rd < 4; ++rd) {
            int dq = kq * 4 + rd * 16;
            kv[rd] = *(const float4*)(krow + dq);
            vv[rd] = *(const float4*)(vrow + dq);
        }
        __syncthreads();                          // prev GEMM2 done reading KPs/Vs
#pragma unroll
        for (int rd = 0; rd < 4; ++rd) {
            int dq = kq * 4 + rd * 16;
            KPs[dq + 0][r] = kv[rd].x;
            KPs[dq + 1][r] = kv[rd].y;
            KPs[dq + 2][r] = kv[rd].z;
            KPs[dq + 3][r] = kv[rd].w;
            *(float4*)&Vs[r][dq] = vv[rd];
        }
        __syncthreads();

        // ---- GEMM1: T[kpos][q] = K @ Q^T ----
        float s[4][4] = {{0.f}};
#pragma unroll 8
        for (int kk = 0; kk < 64; ++kk) {
            float4 a4 = *(const float4*)&KPs[kk][ty * 4];
            float4 b4 = *(const float4*)&Qs[kk][tx * 4];
            float aa[4] = {a4.x, a4.y, a4.z, a4.w};
            float bb[4] = {b4.x, b4.y, b4.z, b4.w};
#pragma unroll
            for (int i = 0; i < 4; ++i)
#pragma unroll
                for (int j = 0; j < 4; ++j) s[i][j] += aa[i] * bb[j];
        }
        __syncthreads();                          // done reading KPs as K

        // ---- scale + causal mask ----
        bool diag = (kt == by);
        int kbase = kt * 64 + ty * 4;
#pragma unroll
        for (int i = 0; i < 4; ++i)
#pragma unroll
            for (int j = 0; j < 4; ++j) {
                float sv = s[i][j] * scale;
                if (diag && (kbase + i) > (q0 + tx * 4 + j)) sv = -1e30f;
                s[i][j] = sv;
            }

        // ---- online softmax along kpos (column j stats) ----
#pragma unroll
        for (int j = 0; j < 4; ++j) {
            float cm = fmaxf(fmaxf(s[0][j], s[1][j]), fmaxf(s[2][j], s[3][j]));
#pragma unroll
            for (int off = 8; off > 0; off >>= 1) cm = fmaxf(cm, __shfl_xor(cm, off));
            float mnew = fmaxf(mreg[j], cm);
            float corr = expf(mreg[j] - mnew);
            float ps = 0.f;
#pragma unroll
            for (int i = 0; i < 4; ++i) {
                float p = expf(s[i][j] - mnew);
                s[i][j] = p;
                ps += p;
            }
#pragma unroll
            for (int off = 8; off > 0; off >>= 1) ps += __shfl_xor(ps, off);
            lreg[j] = lreg[j] * corr + ps;
            mreg[j] = mnew;
#pragma unroll
            for (int i = 0; i < 4; ++i) acc[i][j] *= corr;
        }

        // ---- write P^T[kpos][q] into KPs ----
#pragma unroll
        for (int i = 0; i < 4; ++i)
            *(float4*)&KPs[ty * 4 + i][tx * 4] =
                make_float4(s[i][0], s[i][1], s[i][2], s[i][3]);
        __syncthreads();

        // ---- GEMM2: O^T[d][q] += V^T @ P^T ----
#pragma unroll 8
        for (int kk = 0; kk < 64; ++kk) {
            float4 a4 = *(const float4*)&Vs[kk][ty * 4];
            float4 b4 = *(const float4*)&KPs[kk][tx * 4];
            float aa[4] = {a4.x, a4.y, a4.z, a4.w};
            float bb[4] = {b4.x, b4.y, b4.z, b4.w};
#pragma unroll
            for (int i = 0; i < 4; ++i)
#pragma unroll
                for (int j = 0; j < 4; ++j) acc[i][j] += aa[i] * bb[j];
        }
    }

    // ---- normalize, transpose through LDS, coalesced store ----
    __syncthreads();                              // last GEMM2 reads done
#pragma unroll
    for (int i = 0; i < 4; ++i)
#pragma unroll
        for (int j = 0; j < 4; ++j)
            KPs[tx * 4 + j][ty * 4 + i] = acc[i][j] / lreg[j];   // O[q][d]
    __syncthreads();
    {
        int r = tid >> 2, kq = tid & 3;
        float* orow = o + (long)(b * S_LEN + q0 + r) * DIM + h * HD;
#pragma unroll
        for (int rd = 0; rd < 4; ++rd) {
            int col = kq * 4 + rd * 16;
            *(float4*)(orow + col) = *(const float4*)&KPs[r][col];
        }
    }
}

// ---------------------------------------------------------------------------
// gate: logits = xn @ gate_w (1024x8), softmax, top-2, renormalize
__global__ void gate_k(const float* __restrict__ xn, const float* __restrict__ gw,
                       int* __restrict__ tke, float* __restrict__ tkw,
                       int* __restrict__ cnt) {
    int t = blockIdx.x;
    __shared__ float pl[256];
    __shared__ float lg[8];
    int e = threadIdx.x & 7, c = threadIdx.x >> 3;
    const float* xr = xn + (long)t * DIM;
    float s = 0.f;
    for (int i = 0; i < DIM / 32; ++i) {
        int d = c + i * 32;
        s += xr[d] * gw[d * 8 + e];
    }
    pl[threadIdx.x] = s;
    __syncthreads();
    if (threadIdx.x < 8) {
        float sum = 0.f;
        for (int c2 = 0; c2 < 32; ++c2) sum += pl[c2 * 8 + threadIdx.x];
        lg[threadIdx.x] = sum;
    }
    __syncthreads();
    if (threadIdx.x == 0) {
        float mx = lg[0];
        for (int i = 1; i < 8; ++i) mx = fmaxf(mx, lg[i]);
        float pe[8];
        for (int i = 0; i < 8; ++i) pe[i] = expf(lg[i] - mx);
        int i0 = 0;
        for (int i = 1; i < 8; ++i) if (pe[i] > pe[i0]) i0 = i;
        int i1 = -1;
        for (int i = 0; i < 8; ++i) {
            if (i == i0) continue;
            if (i1 < 0 || pe[i] > pe[i1]) i1 = i;
        }
        float w0 = pe[i0], w1 = pe[i1];
        float wsum = w0 + w1;
        w0 /= wsum; w1 /= wsum;
        tke[2 * t] = i0; tke[2 * t + 1] = i1;
        tkw[2 * t] = w0; tkw[2 * t + 1] = w1;
        atomicAdd(&cnt[i0], 1);
        atomicAdd(&cnt[i1], 1);
    }
}

// padded prefix sums of expert counts (pad each segment to 128 rows)
__global__ void offs_k(const int* __restrict__ cnt, int* __restrict__ offs) {
    if (threadIdx.x == 0) {
        int o = 0;
        for (int e = 0; e < NEXP; ++e) { offs[e] = o; o += (cnt[e] + 127) & ~127; }
        offs[NEXP] = o;
    }
}

// per-token slot assignment
__global__ void fill_k(const int* __restrict__ tke, const float* __restrict__ tkw,
                       const int* __restrict__ offs, int* __restrict__ fillc,
                       int* __restrict__ rowidx, int* __restrict__ tslot) {
    int t = blockIdx.x * 256 + threadIdx.x;
    if (t >= NTOK) return;
    for (int kk = 0; kk < 2; ++kk) {
        int e = tke[2 * t + kk];
        int pos = atomicAdd(&fillc[e], 1);
        int slot = offs[e] + pos;
        rowidx[slot] = t;
        tslot[2 * t + kk] = slot;
    }
}

// h[t] += w0*eout[s0] + w1*eout[s1]
__global__ void combine_k(const int* __restrict__ tslot, const float* __restrict__ tkw,
                          const float* __restrict__ eout, float* __restrict__ h) {
    int t = blockIdx.x;
    int s0 = tslot[2 * t], s1 = tslot[2 * t + 1];
    float w0 = tkw[2 * t], w1 = tkw[2 * t + 1];
    float* hr = h + (long)t * DIM;
    const float* e0 = eout + (long)s0 * DIM;
    const float* e1 = eout + (long)s1 * DIM;
    for (int d = threadIdx.x; d < DIM; d += 256)
        hr[d] += w0 * e0[d] + w1 * e1[d];
}

// in-place silu-mul over the up-projection scratch: x1 = silu(x1) * x3
// hh2 row layout: [ x1 (2816) | x3 (2816) ], one block per row
__global__ void silumul_k(float* __restrict__ hh2) {
    int r = blockIdx.x;
    float* x1 = hh2 + (long)r * (2 * HIDDEN);
    const float* x3 = x1 + HIDDEN;
    for (int c = threadIdx.x; c < HIDDEN; c += 256) {
        float a = x1[c];
        x1[c] = a / (1.f + expf(-a)) * x3[c];
    }
}

// ---------------------------------------------------------------------------
// tiled fp32 GEMM: 128x128 tile, BK=16, 256 threads, 8x8 per thread.
// Column split: logical col n < Nsplit -> B/C at col n, else B2/C2 at n-Nsplit.
// MODE 0: C = A@B
// MODE 1: C += A@B
// MODE 2: expert-segmented m-tiles, A rows gathered via rowidx
// MODE 3: expert-segmented m-tiles, A rows contiguous
template <int MODE>
__global__ __launch_bounds__(256, 3) void gemm_k(
    const float* __restrict__ A, const float* __restrict__ B,
    const float* __restrict__ B2, float* __restrict__ C, float* __restrict__ C2,
    int N, int Nsplit, int K, int lda, int ldb, int ldc,
    const int* __restrict__ offs, const int* __restrict__ cnt,
    const int* __restrict__ rowidx) {
    __shared__ __align__(16) float As[16][132];   // k-major, +4 pad breaks write conflicts
    __shared__ __align__(16) float Bs[16][132];

    int n0 = blockIdx.x * 128, m0 = blockIdx.y * 128;
    const float* Bbase = B;
    float* Cbase = C;
    int ncol = n0;
    if (n0 >= Nsplit) { Bbase = B2; Cbase = C2; ncol = n0 - Nsplit; }

    int vr = 128;
    if (MODE >= 2) {
        int e = -1;
#pragma unroll
        for (int i = 0; i < NEXP; ++i)
            if (m0 >= offs[i] && m0 < offs[i + 1]) e = i;
        if (e < 0) return;
        vr = offs[e] + cnt[e] - m0;
        if (vr <= 0) return;
        if (vr > 128) vr = 128;
        Bbase += (long)e * K * ldb;
    }
    const float* Bp = Bbase + ncol;
    float* Cp = Cbase + ncol;

    int tid = threadIdx.x;
    int tx = tid & 15, ty = tid >> 4;

    // A staging: each thread loads rows r0 and r0+64, k-quad kq..kq+3
    int r0 = tid >> 2, kq = (tid & 3) * 4;
    long aoff0, aoff1;
    if (MODE == 2) {
        int g0 = (r0 < vr) ? rowidx[m0 + r0] : 0;
        int g1 = (r0 + 64 < vr) ? rowidx[m0 + r0 + 64] : 0;
        aoff0 = (long)g0 * lda;
        aoff1 = (long)g1 * lda;
    } else {
        aoff0 = (long)(m0 + r0) * lda;
        aoff1 = (long)(m0 + r0 + 64) * lda;
    }
    // B staging: each thread loads row bk, col quads bn4 and bn4+64
    int bk = tid >> 4, bn4 = (tid & 15) * 4;

    float acc[8][8] = {{0.f}};

    for (int k0 = 0; k0 < K; k0 += 16) {
        float4 av0 = *(const float4*)(A + aoff0 + k0 + kq);
        float4 av1 = *(const float4*)(A + aoff1 + k0 + kq);
        const float* brow = Bp + (long)(k0 + bk) * ldb + bn4;
        float4 bv0 = *(const float4*)(brow);
        float4 bv1 = *(const float4*)(brow + 64);
        __syncthreads();
        As[kq + 0][r0] = av0.x;
        As[kq + 1][r0] = av0.y;
        As[kq + 2][r0] = av0.z;
        As[kq + 3][r0] = av0.w;
        As[kq + 0][r0 + 64] = av1.x;
        As[kq + 1][r0 + 64] = av1.y;
        As[kq + 2][r0 + 64] = av1.z;
        As[kq + 3][r0 + 64] = av1.w;
        *(float4*)&Bs[bk][bn4] = bv0;
        *(float4*)&Bs[bk][bn4 + 64] = bv1;
        __syncthreads();
#pragma unroll
        for (int kk = 0; kk < 16; ++kk) {
            float4 a0 = *(const float4*)&As[kk][ty * 4];
            float4 a1 = *(const float4*)&As[kk][ty * 4 + 64];
            float4 b0 = *(const float4*)&Bs[kk][tx * 4];
            float4 b1 = *(const float4*)&Bs[kk][tx * 4 + 64];
            float aa[8] = {a0.x, a0.y, a0.z, a0.w, a1.x, a1.y, a1.z, a1.w};
            float bb[8] = {b0.x, b0.y, b0.z, b0.w, b1.x, b1.y, b1.z, b1.w};
#pragma unroll
            for (int i = 0; i < 8; ++i)
#pragma unroll
                for (int j = 0; j < 8; ++j) acc[i][j] += aa[i] * bb[j];
        }
    }

#pragma unroll
    for (int i = 0; i < 8; ++i) {
        int r = (i < 4) ? (ty * 4 + i) : (ty * 4 + i - 4 + 64);
        if (MODE >= 2 && r >= vr) continue;
        float* cp = Cp + (long)(m0 + r) * ldc + tx * 4;
        float4 v0 = make_float4(acc[i][0], acc[i][1], acc[i][2], acc[i][3]);
        float4 v1 = make_float4(acc[i][4], acc[i][5], acc[i][6], acc[i][7]);
        if (MODE == 1) {
            float4 o0 = *(const float4*)cp;
            float4 o1 = *(const float4*)(cp + 64);
            v0.x += o0.x; v0.y += o0.y; v0.z += o0.z; v0.w += o0.w;
            v1.x += o1.x; v1.y += o1.y; v1.z += o1.z; v1.w += o1.w;
        }
        *(float4*)cp = v0;
        *(float4*)(cp + 64) = v1;
    }
}

// ---------------------------------------------------------------------------
extern "C" void kernel_launch(void* const* d_in, const int* in_sizes, int n_in,
                              void* d_out, int out_size, void* d_ws, size_t ws_size,
                              hipStream_t stream) {
    const int*   tokens = (const int*)d_in[0];
    const int*   sposp  = (const int*)d_in[1];
    const float* emb    = (const float*)d_in[2];
    const float* anw    = (const float*)d_in[3];
    const float* wq     = (const float*)d_in[4];
    const float* wk     = (const float*)d_in[5];
    const float* wv     = (const float*)d_in[6];
    const float* wo     = (const float*)d_in[7];
    const float* fnw    = (const float*)d_in[8];
    const float* gw     = (const float*)d_in[9];
    const float* w1     = (const float*)d_in[10];
    const float* w2     = (const float*)d_in[11];
    const float* w3     = (const float*)d_in[12];
    const float* nw     = (const float*)d_in[13];
    const float* ow     = (const float*)d_in[14];
    float* out = (float*)d_out;

    char* wsb = (char*)d_ws;
    float* h  = (float*)wsb;                 wsb += (long)NTOK * DIM * 4;
    float* xn = (float*)wsb;                 wsb += (long)NTOK * DIM * 4;
    float* q  = (float*)wsb;                 wsb += (long)NTOK * DIM * 4;
    float* kb = (float*)wsb;                 wsb += (long)NTOK * NKVH * HD * 4;
    float* vb = (float*)wsb;                 wsb += (long)NTOK * NKVH * HD * 4;
    float* ao = (float*)wsb;                 wsb += (long)NTOK * DIM * 4;
    float* tkw = (float*)wsb;                wsb += (long)NTOK * 2 * 4;
    int* tke    = (int*)wsb;                 wsb += (long)NTOK * 2 * 4;
    int* tslot  = (int*)wsb;                 wsb += (long)NTOK * 2 * 4;
    int* rowidx = (int*)wsb;                 wsb += (long)MOE_ROWS * 4;
    int* cnt    = (int*)wsb;                 wsb += 8 * 4;
    int* fillc  = (int*)wsb;                 wsb += 8 * 4;
    int* offs   = (int*)wsb;                 wsb += 16 * 4;

    // big MoE scratch lives in d_out (fully overwritten by final logits GEMM)
    // hh2: MOE_ROWS x 5632  raw [x@w1 | x@w3], silu-mul'd in place (first half)
    // eout: MOE_ROWS x DIM  expert outputs
    float* hh2  = out;
    float* eout = out + (long)MOE_ROWS * (2 * HIDDEN);
    // usage: 9216*(5632+1024)*4B = 245 MB < out_size (4096*32000*4B = 524 MB)

    embed_k<<<NTOK, 256, 0, stream>>>(tokens, emb, h);

    for (int l = 0; l < 2; ++l) {
        const float* wq_l = wq + (long)l * DIM * DIM;
        const float* wk_l = wk + (long)l * DIM * (NKVH * HD);
        const float* wv_l = wv + (long)l * DIM * (NKVH * HD);
        const float* wo_l = wo + (long)l * DIM * DIM;
        const float* gw_l = gw + (long)l * DIM * NEXP;
        const float* w1_l = w1 + (long)l * NEXP * DIM * HIDDEN;
        const float* w2_l = w2 + (long)l * NEXP * HIDDEN * DIM;
        const float* w3_l = w3 + (long)l * NEXP * DIM * HIDDEN;

        // attention
        rmsnorm_k<<<NTOK, 256, 0, stream>>>(h, anw + l * DIM, xn);
        gemm_k<0><<<dim3(DIM / 128, NTOK / 128), 256, 0, stream>>>(
            xn, wq_l, nullptr, q, nullptr,
            DIM, DIM, DIM, DIM, DIM, DIM, nullptr, nullptr, nullptr);
        // fused K|V projection (column split at 256)
        gemm_k<0><<<dim3((2 * NKVH * HD) / 128, NTOK / 128), 256, 0, stream>>>(
            xn, wk_l, wv_l, kb, vb,
            2 * NKVH * HD, NKVH * HD, DIM, DIM, NKVH * HD, NKVH * HD,
            nullptr, nullptr, nullptr);
        rope_k<<<(NTOK * NHEADS * 32) / 256, 256, 0, stream>>>(q, 4, sposp, NTOK * NHEADS * 32);
        rope_k<<<(NTOK * NKVH * 32) / 256, 256, 0, stream>>>(kb, 2, sposp, NTOK * NKVH * 32);
        attn_fa_k<<<dim3(BATCH * NHEADS, S_LEN / 64), 256, 0, stream>>>(q, kb, vb, ao);
        gemm_k<1><<<dim3(DIM / 128, NTOK / 128), 256, 0, stream>>>(
            ao, wo_l, nullptr, h, nullptr,
            DIM, DIM, DIM, DIM, DIM, DIM, nullptr, nullptr, nullptr);

        // MoE
        rmsnorm_k<<<NTOK, 256, 0, stream>>>(h, fnw + l * DIM, xn);
        hipMemsetAsync(cnt, 0, 16 * sizeof(int), stream);  // cnt + fillc
        gate_k<<<NTOK, 256, 0, stream>>>(xn, gw_l, tke, tkw, cnt);
        offs_k<<<1, 64, 0, stream>>>(cnt, offs);
        fill_k<<<NTOK / 256, 256, 0, stream>>>(tke, tkw, offs, fillc, rowidx, tslot);
        // up: hh2 = [xg @ w1 | xg @ w3], gathered rows, column split at 2816
        gemm_k<2><<<dim3((2 * HIDDEN) / 128, MOE_ROWS / 128), 256, 0, stream>>>(
            xn, w1_l, w3_l, hh2, hh2 + HIDDEN,
            2 * HIDDEN, HIDDEN, DIM, DIM, HIDDEN, 2 * HIDDEN, offs, cnt, rowidx);
        silumul_k<<<MOE_ROWS, 256, 0, stream>>>(hh2);
        // down: eout = hh2[:, :2816] @ w2   (lda = 5632)
        gemm_k<3><<<dim3(DIM / 128, MOE_ROWS / 128), 256, 0, stream>>>(
            hh2, w2_l, nullptr, eout, nullptr,
            DIM, DIM, HIDDEN, 2 * HIDDEN, DIM, DIM, offs, cnt, nullptr);
        combine_k<<<NTOK, 256, 0, stream>>>(tslot, tkw, eout, h);
    }

    // final norm + logits
    rmsnorm_k<<<NTOK, 256, 0, stream>>>(h, nw, xn);
    gemm_k<0><<<dim3(VOCABSZ / 128, NTOK / 128), 256, 0, stream>>>(
        xn, ow, nullptr, out, nullptr,
        VOCABSZ, VOCABSZ, DIM, DIM, VOCABSZ, VOCABSZ, nullptr, nullptr, nullptr);
}